// Round 7
// baseline (1073.888 us; speedup 1.0000x reference)
//
#include <hip/hip_runtime.h>
#include <hip/hip_cooperative_groups.h>

namespace cg = cooperative_groups;

typedef unsigned short u16;

#define NT   16384
#define LAYERS 6
#define LDP  264   // padded LDS row length (elements); 264%8==0 keeps b128 aligned

using bf16x8 = __attribute__((ext_vector_type(8))) __bf16;
using f32x4  = __attribute__((ext_vector_type(4))) float;

#define MFMA __builtin_amdgcn_mfma_f32_16x16x32_bf16

__device__ __forceinline__ u16 f2bf(float x){
  unsigned u = __float_as_uint(x);
  u += 0x7fffu + ((u >> 16) & 1u);
  return (u16)(u >> 16);
}
__device__ __forceinline__ float bf2f(u16 u){
  return __uint_as_float(((unsigned)u) << 16);
}

// ---------------------------------------------------------------------------
// Weight transpose+convert: fp32 [K=256][N] -> bf16 [Npad][256] (row n = W[:,n])
// ---------------------------------------------------------------------------
__global__ __launch_bounds__(256) void wconv_k(
    const float* __restrict__ Wq, const float* __restrict__ Wk,
    const float* __restrict__ Wv, const float* __restrict__ Wo,
    const float* __restrict__ W1, const float* __restrict__ W2,
    const float* __restrict__ Wlm, u16* __restrict__ WT)
{
  __shared__ float tile[64][65];
  const int z = blockIdx.z;
  const float* src; u16* dst; int N = 256, Npad = 256;
  if (z < 18){
    const int l = z / 3, which = z % 3;
    const float* a[3] = {Wq, Wk, Wv};
    src = a[which] + (size_t)l * 65536;
    dst = WT + (size_t)l * 196608 + (size_t)which * 65536;
  } else if (z < 36){
    const int i = z - 18, j = i / 6, l = i % 6;
    const float* a[3] = {Wo, W1, W2};
    src = a[j] + (size_t)l * 65536;
    dst = WT + 1179648 + (size_t)(j * 6 + l) * 65536;
  } else {
    src = Wlm; dst = WT + 2359296; N = 96; Npad = 128;
  }
  const int n0 = blockIdx.y * 64, k0 = blockIdx.x * 64;
  if (n0 >= Npad) return;
  const int c = threadIdx.x & 63, r0 = threadIdx.x >> 6;
  #pragma unroll
  for (int i = 0; i < 16; ++i){
    const int r = r0 + i * 4;
    tile[r][c] = (n0 + c < N) ? src[(size_t)(k0 + r) * N + n0 + c] : 0.f;
  }
  __syncthreads();
  #pragma unroll
  for (int i = 0; i < 16; ++i){
    const int cp = r0 + i * 4;
    dst[(size_t)(n0 + cp) * 256 + k0 + c] = f2bf(tile[c][cp]);
  }
}

// ---------------------------------------------------------------------------
// 64-row tile GEMM helper: out = A[64][256] @ W^T-layout B + epilogue.
// Waves 2x4 (rows (w>>2)*32, cols (w&3)*64). A from LDS (stride LDP) or
// global (stride 256). LNEP: +bias +res(XT) -> LN -> XT. else: +bias,ReLU->Hout.
// ---------------------------------------------------------------------------
template<bool LNEP>
__device__ __forceinline__ void gemm64(
    const u16* __restrict__ Ab, const int astride,
    const u16* __restrict__ Bw, const float* __restrict__ bias,
    const float* __restrict__ lnw, const float* __restrict__ lnb,
    u16* __restrict__ XT, u16* __restrict__ Hout,
    float* __restrict__ redA, float* __restrict__ redB,
    const int w, const int lr, const int lk, const int rj)
{
  const int rb = (w >> 2) * 32, cb = (w & 3) * 64, wc = w & 3;
  f32x4 acc[2][4] = {};
  #pragma unroll
  for (int kk = 0; kk < 256; kk += 32){
    bf16x8 af[2], bf[4];
    #pragma unroll
    for (int m = 0; m < 2; ++m)
      af[m] = *reinterpret_cast<const bf16x8*>(Ab + (size_t)(rb + m*16 + lr) * astride + kk + lk);
    #pragma unroll
    for (int n = 0; n < 4; ++n)
      bf[n] = *reinterpret_cast<const bf16x8*>(Bw + (size_t)(cb + n*16 + lr) * 256 + kk + lk);
    #pragma unroll
    for (int m = 0; m < 2; ++m)
      #pragma unroll
      for (int n = 0; n < 4; ++n)
        acc[m][n] = MFMA(af[m], bf[n], acc[m][n], 0, 0, 0);
  }
  if (LNEP){
    #pragma unroll
    for (int m = 0; m < 2; ++m){
      #pragma unroll
      for (int j = 0; j < 4; ++j){
        const int row = rb + m*16 + rj + j;
        float s = 0.f, q = 0.f;
        #pragma unroll
        for (int n = 0; n < 4; ++n){
          const int col = cb + n*16 + lr;
          float v = acc[m][n][j] + bias[col] + bf2f(XT[row*LDP + col]);
          acc[m][n][j] = v;
          s += v; q += v * v;
        }
        #pragma unroll
        for (int o = 1; o < 16; o <<= 1){ s += __shfl_xor(s, o); q += __shfl_xor(q, o); }
        if (lr == 0){ redA[row*4 + wc] = s; redB[row*4 + wc] = q; }
      }
    }
    __syncthreads();
    #pragma unroll
    for (int m = 0; m < 2; ++m){
      #pragma unroll
      for (int j = 0; j < 4; ++j){
        const int row = rb + m*16 + rj + j;
        float s = 0.f, q = 0.f;
        #pragma unroll
        for (int c = 0; c < 4; ++c){ s += redA[row*4 + c]; q += redB[row*4 + c]; }
        const float mean = s * (1.f/256.f);
        const float rstd = rsqrtf(q * (1.f/256.f) - mean*mean + 1e-5f);
        #pragma unroll
        for (int n = 0; n < 4; ++n){
          const int col = cb + n*16 + lr;
          XT[row*LDP + col] = f2bf((acc[m][n][j] - mean) * rstd * lnw[col] + lnb[col]);
        }
      }
    }
  } else {
    #pragma unroll
    for (int m = 0; m < 2; ++m)
      #pragma unroll
      for (int n = 0; n < 4; ++n){
        const int col = cb + n*16 + lr;
        #pragma unroll
        for (int j = 0; j < 4; ++j){
          const int row = rb + m*16 + rj + j;
          Hout[row*LDP + col] = f2bf(fmaxf(acc[m][n][j] + bias[col], 0.f));
        }
      }
  }
}

// ---------------------------------------------------------------------------
// Mega-kernel: whole forward. 256 blocks x 512 threads, cooperative.
// Block bi owns rows [bi*64, bi*64+64). LDS: XT(residual) | R1(Q/h/Xf) | PS |
// VT | red. KV double-buffered in global (parity per layer); O via global
// (same-block L2). One grid.sync per layer (QKV->attn) + one for the loss.
// ---------------------------------------------------------------------------
__global__ __launch_bounds__(512) void mega_k(
    const int* __restrict__ idx, const int* __restrict__ target,
    const float* __restrict__ tok, const float* __restrict__ pos,
    const u16* __restrict__ WT,
    const float* __restrict__ bo, const float* __restrict__ b1,
    const float* __restrict__ b2,
    const float* __restrict__ ln1w, const float* __restrict__ ln1b,
    const float* __restrict__ ln2w, const float* __restrict__ ln2b,
    const float* __restrict__ lnfw, const float* __restrict__ lnfb,
    const float* __restrict__ blm,
    u16* __restrict__ KV0, u16* __restrict__ KV1, u16* __restrict__ Obuf,
    float* __restrict__ nl, float* __restrict__ out)
{
  extern __shared__ char smem[];
  u16* XT = (u16*)smem;                       // [64][LDP] residual (bf16)
  u16* R1 = (u16*)(smem + 33792);             // [64][LDP] Q-tile / h / Xf
  u16* PS = (u16*)(smem + 2*33792);           // [64][LDP] attn P
  u16* VT = (u16*)(smem + 3*33792);           // [32][LDP] V^T per head
  float* redA = (float*)(smem + 3*33792 + 16896);
  float* redB = redA + 256;
  float* redC = redB + 256;

  cg::grid_group grid = cg::this_grid();

  const int t = threadIdx.x, l = t & 63, w = t >> 6;
  const int lr = l & 15, lk = (l >> 4) * 8, rj = (l >> 4) * 4;
  const int bi = blockIdx.x;
  const int row0 = bi * 64;
  const int brow = (bi >> 2) * 256;   // batch start row
  const int tq0  = (bi & 3) * 64;     // q position offset within batch

  // ---- embed: XT = bf16(tok[idx] + pos) ----
  {
    const int r = t >> 3, c0 = (t & 7) * 32;
    const int gr = row0 + r;
    const int id = idx[gr];
    #pragma unroll
    for (int i = 0; i < 32; i += 4){
      float4 tv = *reinterpret_cast<const float4*>(tok + (size_t)id * 256 + c0 + i);
      float4 pv = *reinterpret_cast<const float4*>(pos + (size_t)(gr & 255) * 256 + c0 + i);
      union{u16 u[4]; uint2 q;} p;
      p.u[0] = f2bf(tv.x + pv.x); p.u[1] = f2bf(tv.y + pv.y);
      p.u[2] = f2bf(tv.z + pv.z); p.u[3] = f2bf(tv.w + pv.w);
      *reinterpret_cast<uint2*>(XT + r*LDP + c0 + i) = p.q;
    }
  }
  __syncthreads();

  #pragma unroll 1
  for (int ly = 0; ly < LAYERS; ++ly){
    u16* KV = (ly & 1) ? KV1 : KV0;
    const u16* wqkv = WT + (size_t)ly * 196608;
    const u16* wo = WT + 1179648 + (size_t)(0*6+ly)*65536;
    const u16* w1 = WT + 1179648 + (size_t)(1*6+ly)*65536;
    const u16* w2 = WT + 1179648 + (size_t)(2*6+ly)*65536;

    // ---- QKV: [64][768] = XT @ wqkv; Q -> R1 (LDS), K/V -> KV (global) ----
    {
      f32x4 acc[4][6] = {};
      #pragma unroll
      for (int kk = 0; kk < 256; kk += 32){
        bf16x8 af[4], bf[6];
        #pragma unroll
        for (int m = 0; m < 4; ++m)
          af[m] = *reinterpret_cast<const bf16x8*>(XT + (m*16 + lr)*LDP + kk + lk);
        #pragma unroll
        for (int n = 0; n < 6; ++n)
          bf[n] = *reinterpret_cast<const bf16x8*>(wqkv + (size_t)(w*96 + n*16 + lr)*256 + kk + lk);
        #pragma unroll
        for (int m = 0; m < 4; ++m)
          #pragma unroll
          for (int n = 0; n < 6; ++n)
            acc[m][n] = MFMA(af[m], bf[n], acc[m][n], 0, 0, 0);
      }
      #pragma unroll
      for (int m = 0; m < 4; ++m)
        #pragma unroll
        for (int n = 0; n < 6; ++n){
          const int col = w*96 + n*16 + lr;
          #pragma unroll
          for (int j = 0; j < 4; ++j){
            const int row = m*16 + rj + j;
            const u16 v = f2bf(acc[m][n][j]);
            if (col < 256) R1[row*LDP + col] = v;
            else KV[(size_t)(row0 + row)*512 + col - 256] = v;
          }
        }
    }
    grid.sync();

    // ---- attention: 8 heads sequential; waves = 4 row-groups x 2 k-halves ----
    {
      const int rg = w >> 1, kh = w & 1;
      #pragma unroll 1
      for (int h = 0; h < 8; ++h){
        // stage V^T [32][256]
        #pragma unroll
        for (int it = 0; it < 2; ++it){
          const int tk = t >> 1, d0 = ((t & 1) + 2*it) * 8;
          union{uint4 q; u16 u[8];} p;
          p.q = *reinterpret_cast<const uint4*>(KV + (size_t)(brow + tk)*512 + 256 + h*32 + d0);
          #pragma unroll
          for (int k2 = 0; k2 < 8; ++k2) VT[(d0 + k2)*LDP + tk] = p.u[k2];
        }
        bf16x8 kf[8];
        #pragma unroll
        for (int n = 0; n < 8; ++n)
          kf[n] = *reinterpret_cast<const bf16x8*>(KV + (size_t)(brow + kh*128 + n*16 + lr)*512 + h*32 + lk);
        bf16x8 qa = *reinterpret_cast<const bf16x8*>(R1 + (rg*16 + lr)*LDP + h*32 + lk);
        f32x4 sf[8];
        #pragma unroll
        for (int n = 0; n < 8; ++n){ f32x4 z = {}; sf[n] = MFMA(qa, kf[n], z, 0, 0, 0); }
        #pragma unroll
        for (int j = 0; j < 4; ++j){
          const int tq = tq0 + rg*16 + rj + j;
          float m = -1e30f;
          #pragma unroll
          for (int n = 0; n < 8; ++n){
            const int tk = kh*128 + n*16 + lr;
            float v = sf[n][j] * 0.0625f;
            v = (tk <= tq) ? v : -1e30f;
            sf[n][j] = v;
            m = fmaxf(m, v);
          }
          #pragma unroll
          for (int o = 1; o < 16; o <<= 1) m = fmaxf(m, __shfl_xor(m, o));
          if (lr == 0) redA[(rg*16 + rj + j)*2 + kh] = m;
        }
        __syncthreads();   // barA: partial maxes + VT staged
        #pragma unroll
        for (int j = 0; j < 4; ++j){
          const int r = rg*16 + rj + j;
          const float m = fmaxf(redA[r*2], redA[r*2 + 1]);
          float s = 0.f;
          #pragma unroll
          for (int n = 0; n < 8; ++n){
            const float p = __expf(sf[n][j] - m);
            s += p;
            PS[r*LDP + kh*128 + n*16 + lr] = f2bf(p);
          }
          #pragma unroll
          for (int o = 1; o < 16; o <<= 1) s += __shfl_xor(s, o);
          if (lr == 0) redB[r*2 + kh] = s;
        }
        __syncthreads();   // barB: PS + partial sums
        f32x4 o4 = {};
        #pragma unroll
        for (int kk = 0; kk < 8; ++kk){
          bf16x8 pa = *reinterpret_cast<const bf16x8*>(PS + (rg*16 + lr)*LDP + kk*32 + lk);
          bf16x8 vb = *reinterpret_cast<const bf16x8*>(VT + (kh*16 + lr)*LDP + kk*32 + lk);
          o4 = MFMA(pa, vb, o4, 0, 0, 0);
        }
        #pragma unroll
        for (int j = 0; j < 4; ++j){
          const int r = rg*16 + rj + j;
          const float inv = 1.f / (redB[r*2] + redB[r*2 + 1]);
          Obuf[(size_t)(row0 + r)*256 + h*32 + kh*16 + lr] = f2bf(o4[j] * inv);
        }
        __syncthreads();   // barC: PS/VT/red free; Obuf drained (vmcnt at barrier)
      }
    }

    // ---- Wo + residual + LN1 -> XT ----
    gemm64<true >(Obuf + (size_t)row0*256, 256, wo, bo + ly*256,
                  ln1w + ly*256, ln1b + ly*256, XT, nullptr, redA, redB, w, lr, lk, rj);
    __syncthreads();
    // ---- W1 + ReLU -> R1 (h) ----
    gemm64<false>(XT, LDP, w1, b1 + ly*256, nullptr, nullptr,
                  XT, R1, redA, redB, w, lr, lk, rj);
    __syncthreads();
    // ---- W2 + residual + LN2 -> XT ----
    gemm64<true >(R1, LDP, w2, b2 + ly*256,
                  ln2w + ly*256, ln2b + ly*256, XT, nullptr, redA, redB, w, lr, lk, rj);
    __syncthreads();
  }

  // ---- final LN: XT -> R1 ----
  {
    const int r = t >> 3, c0 = (t & 7) * 32;
    float va[32]; float s = 0.f, q = 0.f;
    #pragma unroll
    for (int i = 0; i < 32; ++i){
      va[i] = bf2f(XT[r*LDP + c0 + i]); s += va[i]; q += va[i]*va[i];
    }
    #pragma unroll
    for (int o = 1; o < 8; o <<= 1){ s += __shfl_xor(s, o); q += __shfl_xor(q, o); }
    const float mean = s * (1.f/256.f);
    const float rstd = rsqrtf(q * (1.f/256.f) - mean*mean + 1e-5f);
    #pragma unroll
    for (int i = 0; i < 32; i += 4){
      union{u16 u[4]; uint2 qq;} p;
      #pragma unroll
      for (int k2 = 0; k2 < 4; ++k2)
        p.u[k2] = f2bf((va[i+k2] - mean) * rstd * lnfw[c0+i+k2] + lnfb[c0+i+k2]);
      *reinterpret_cast<uint2*>(R1 + r*LDP + c0 + i) = p.qq;
    }
  }
  __syncthreads();

  // ---- LM head + NLL: waves = 4 row-groups x 2 col-halves (48 cols) ----
  {
    const int rg2 = w >> 1, ch = w & 1;
    const u16* wl = WT + 2359296;  // [128][256]
    f32x4 acc[3] = {};
    #pragma unroll
    for (int kk = 0; kk < 256; kk += 32){
      bf16x8 af = *reinterpret_cast<const bf16x8*>(R1 + (rg2*16 + lr)*LDP + kk + lk);
      #pragma unroll
      for (int n = 0; n < 3; ++n){
        bf16x8 bf = *reinterpret_cast<const bf16x8*>(wl + (size_t)(ch*48 + n*16 + lr)*256 + kk + lk);
        acc[n] = MFMA(af, bf, acc[n], 0, 0, 0);
      }
    }
    #pragma unroll
    for (int n = 0; n < 3; ++n){
      const int col = ch*48 + n*16 + lr;
      #pragma unroll
      for (int j = 0; j < 4; ++j){
        acc[n][j] += blm[col];
        out[(size_t)(row0 + rg2*16 + rj + j)*96 + col] = acc[n][j];
      }
    }
    #pragma unroll
    for (int j = 0; j < 4; ++j){
      const int r = rg2*16 + rj + j;
      float m = fmaxf(fmaxf(acc[0][j], acc[1][j]), acc[2][j]);
      #pragma unroll
      for (int o = 1; o < 16; o <<= 1) m = fmaxf(m, __shfl_xor(m, o));
      if (lr == 0) redA[r*2 + ch] = m;
    }
    __syncthreads();
    #pragma unroll
    for (int j = 0; j < 4; ++j){
      const int r = rg2*16 + rj + j;
      const float m = fmaxf(redA[r*2], redA[r*2 + 1]);
      float s = __expf(acc[0][j] - m) + __expf(acc[1][j] - m) + __expf(acc[2][j] - m);
      #pragma unroll
      for (int o = 1; o < 16; o <<= 1) s += __shfl_xor(s, o);
      if (lr == 0) redB[r*2 + ch] = s;
      const int tgt = target[row0 + r];
      const int tc = tgt - ch*48;
      if (tc >= 0 && tc < 48 && lr == (tc & 15)){
        const int tn = tc >> 4;
        redC[r] = (tn == 0) ? acc[0][j] : (tn == 1) ? acc[1][j] : acc[2][j];
      }
    }
    __syncthreads();
    float lsum = 0.f;
    if (ch == 0 && lr == 0){
      #pragma unroll
      for (int j = 0; j < 4; ++j){
        const int r = rg2*16 + rj + j;
        const float m = fmaxf(redA[r*2], redA[r*2 + 1]);
        lsum += logf(redB[r*2] + redB[r*2 + 1]) + m - redC[r];
      }
    }
    #pragma unroll
    for (int o = 1; o < 64; o <<= 1) lsum += __shfl_xor(lsum, o);
    __syncthreads();
    if (l == 0) redA[w] = lsum;
    __syncthreads();
    if (t == 0){
      float tot = 0.f;
      #pragma unroll
      for (int i = 0; i < 8; ++i) tot += redA[i];
      nl[bi] = tot;
    }
  }
  grid.sync();
  if (bi == 0){
    float s = (t < 256) ? nl[t] : 0.f;
    #pragma unroll
    for (int o = 1; o < 64; o <<= 1) s += __shfl_xor(s, o);
    __syncthreads();
    if (l == 0) redA[w] = s;
    __syncthreads();
    if (t == 0){
      float tot = 0.f;
      #pragma unroll
      for (int i = 0; i < 8; ++i) tot += redA[i];
      out[(size_t)NT * 96] = tot * (1.f / NT);
    }
  }
}

// ---------------------------------------------------------------------------
extern "C" void kernel_launch(void* const* d_in, const int* in_sizes, int n_in,
                              void* d_out, int out_size, void* d_ws, size_t ws_size,
                              hipStream_t stream)
{
  const int*   idx    = (const int*)  d_in[0];
  const int*   target = (const int*)  d_in[1];
  const float* tok    = (const float*)d_in[2];
  const float* pos    = (const float*)d_in[3];
  const float* Wq     = (const float*)d_in[4];
  const float* Wk     = (const float*)d_in[5];
  const float* Wv     = (const float*)d_in[6];
  const float* Wo     = (const float*)d_in[7];
  const float* bo     = (const float*)d_in[8];
  const float* W1     = (const float*)d_in[9];
  const float* b1     = (const float*)d_in[10];
  const float* W2     = (const float*)d_in[11];
  const float* b2     = (const float*)d_in[12];
  const float* ln1w   = (const float*)d_in[13];
  const float* ln1b   = (const float*)d_in[14];
  const float* ln2w   = (const float*)d_in[15];
  const float* ln2b   = (const float*)d_in[16];
  const float* lnfw   = (const float*)d_in[17];
  const float* lnfb   = (const float*)d_in[18];
  const float* Wlm    = (const float*)d_in[19];
  const float* blm    = (const float*)d_in[20];
  float* out = (float*)d_out;

  char* ws = (char*)d_ws;
  u16*   KV0  = (u16*)(ws);                    // 16 MiB [NT][512]
  u16*   KV1  = (u16*)(ws + (16u << 20));      // 16 MiB
  u16*   Obuf = (u16*)(ws + (32u << 20));      //  8 MiB [NT][256]
  u16*   WT   = (u16*)(ws + (40u << 20));      // ~4.63 MiB bf16 weights
  float* nl   = (float*)(ws + (46u << 20));    // 1 KiB partials

  wconv_k<<<dim3(4, 4, 37), 256, 0, stream>>>(Wq, Wk, Wv, Wo, W1, W2, Wlm, WT);

  const u16* WTc = WT;
  void* args[] = {
    (void*)&idx, (void*)&target, (void*)&tok, (void*)&pos, (void*)&WTc,
    (void*)&bo, (void*)&b1, (void*)&b2,
    (void*)&ln1w, (void*)&ln1b, (void*)&ln2w, (void*)&ln2b,
    (void*)&lnfw, (void*)&lnfb, (void*)&blm,
    (void*)&KV0, (void*)&KV1, (void*)&Obuf, (void*)&nl, (void*)&out
  };
  // LDS: 3 tiles [64][264] + VT [32][264] (bf16) + 4 KiB red = 122368 B
  hipLaunchCooperativeKernel((void*)mega_k, dim3(256), dim3(512),
                             args, 122368, stream);
}

// Round 9
// 620.428 us; speedup vs baseline: 1.7309x; 1.7309x over previous
//
#include <hip/hip_runtime.h>

typedef unsigned short u16;

#define NT   16384
#define LAYERS 6

using bf16x8 = __attribute__((ext_vector_type(8))) __bf16;
using f32x4  = __attribute__((ext_vector_type(4))) float;

#define MFMA __builtin_amdgcn_mfma_f32_16x16x32_bf16

__device__ __forceinline__ u16 f2bf(float x){
  unsigned u = __float_as_uint(x);
  u += 0x7fffu + ((u >> 16) & 1u);
  return (u16)(u >> 16);
}
__device__ __forceinline__ float bf2f(u16 u){
  return __uint_as_float(((unsigned)u) << 16);
}

// async global->LDS, 16 bytes per lane
__device__ __forceinline__ void gll16(const u16* g, u16* l){
  __builtin_amdgcn_global_load_lds(
      (const __attribute__((address_space(1))) unsigned int*)g,
      (__attribute__((address_space(3))) unsigned int*)l, 16, 0, 0);
}

// ---------------------------------------------------------------------------
// Weight transpose+convert: fp32 [K=256][N] -> bf16 [Npad][256] (row n = W[:,n])
// ---------------------------------------------------------------------------
__global__ __launch_bounds__(256) void wconv_k(
    const float* __restrict__ Wq, const float* __restrict__ Wk,
    const float* __restrict__ Wv, const float* __restrict__ Wo,
    const float* __restrict__ W1, const float* __restrict__ W2,
    const float* __restrict__ Wlm, u16* __restrict__ WT)
{
  __shared__ float tile[64][65];
  const int z = blockIdx.z;
  const float* src; u16* dst; int N = 256, Npad = 256;
  if (z < 18){
    const int l = z / 3, which = z % 3;
    const float* a[3] = {Wq, Wk, Wv};
    src = a[which] + (size_t)l * 65536;
    dst = WT + (size_t)l * 196608 + (size_t)which * 65536;
  } else if (z < 36){
    const int i = z - 18, j = i / 6, l = i % 6;
    const float* a[3] = {Wo, W1, W2};
    src = a[j] + (size_t)l * 65536;
    dst = WT + 1179648 + (size_t)(j * 6 + l) * 65536;
  } else {
    src = Wlm; dst = WT + 2359296; N = 96; Npad = 128;
  }
  const int n0 = blockIdx.y * 64, k0 = blockIdx.x * 64;
  if (n0 >= Npad) return;
  const int c = threadIdx.x & 63, r0 = threadIdx.x >> 6;
  #pragma unroll
  for (int i = 0; i < 16; ++i){
    const int r = r0 + i * 4;
    tile[r][c] = (n0 + c < N) ? src[(size_t)(k0 + r) * N + n0 + c] : 0.f;
  }
  __syncthreads();
  #pragma unroll
  for (int i = 0; i < 16; ++i){
    const int cp = r0 + i * 4;
    dst[(size_t)(n0 + cp) * 256 + k0 + c] = f2bf(tile[c][cp]);
  }
}

// ---------------------------------------------------------------------------
// Embedding: wave per row -> X bf16.
// ---------------------------------------------------------------------------
__global__ __launch_bounds__(256) void embed_k(
    const int* __restrict__ idx, const float* __restrict__ tok,
    const float* __restrict__ pos, u16* __restrict__ X)
{
  const int w = threadIdx.x >> 6, l = threadIdx.x & 63;
  const int r = blockIdx.x * 4 + w;
  const int id = idx[r];
  float4 tv = *reinterpret_cast<const float4*>(tok + (size_t)id * 256 + l * 4);
  float4 pv = *reinterpret_cast<const float4*>(pos + (size_t)(r & 255) * 256 + l * 4);
  union { u16 u[4]; uint2 q; } p;
  p.u[0] = f2bf(tv.x + pv.x); p.u[1] = f2bf(tv.y + pv.y);
  p.u[2] = f2bf(tv.z + pv.z); p.u[3] = f2bf(tv.w + pv.w);
  *reinterpret_cast<uint2*>(X + (size_t)r * 256 + l * 4) = p.q;
}

// ---------------------------------------------------------------------------
// GEMM v3: out[M,N] = A[M,256](bf16) @ W (WT bf16 [Npad][256]).
// BOTH operands staged to LDS via coalesced global_load_lds, double-buffered
// (stage(next) issued before compute(cur) -- T3-minimum). BK=64.
// Epilogues: +bias, +res(bf16), relu, fused post-LN, fp32/bf16 out.
// Dynamic LDS: As[2][TM*64] | Bs[2][TN*64] | redS/redQ[TM][WC+1].
// ---------------------------------------------------------------------------
template<int TM, int TN, int THREADS, int WR, int WC,
         bool BIAS, bool RELU, bool RES, bool LN, bool F32OUT>
__global__ __launch_bounds__(THREADS) void gemm3_k(
    const u16* __restrict__ A, const u16* __restrict__ WT,
    const float* __restrict__ bias, const u16* __restrict__ res,
    void* __restrict__ outp, const float* __restrict__ lnw,
    const float* __restrict__ lnb, int N, int ldo)
{
  constexpr int MR = TM / (WR * 16), NR = TN / (WC * 16);
  extern __shared__ char smem[];
  u16* As = (u16*)smem;
  u16* Bs = As + 2 * TM * 64;
  float* redS = (float*)(Bs + 2 * TN * 64);
  float* redQ = redS + TM * (WC + 1);

  const int t = threadIdx.x, l = t & 63, w = t >> 6;
  const int wr = w / WC, wc = w % WC;
  const int m0 = blockIdx.x * TM, n0 = blockIdx.y * TN;
  const int lr = l & 15, lk = (l >> 4) * 8, rj = (l >> 4) * 4;
  const int rb = wr * (TM / WR), cb = wc * (TN / WC);
  f32x4 acc[MR][NR] = {};

  auto stage = [&](int buf, int kt){
    const int k0 = kt * 64;
    u16* as = As + buf * (TM * 64);
    u16* bs = Bs + buf * (TN * 64);
    #pragma unroll
    for (int ci = t; ci < TM * 8; ci += THREADS){
      const int eo = ci * 8;
      gll16(A + (size_t)(m0 + (eo >> 6)) * 256 + k0 + (eo & 63), as + eo);
    }
    #pragma unroll
    for (int ci = t; ci < TN * 8; ci += THREADS){
      const int eo = ci * 8;
      gll16(WT + (size_t)(n0 + (eo >> 6)) * 256 + k0 + (eo & 63), bs + eo);
    }
  };
  auto compute = [&](int buf){
    const u16* as = As + buf * (TM * 64);
    const u16* bs = Bs + buf * (TN * 64);
    #pragma unroll
    for (int kk = 0; kk < 64; kk += 32){
      bf16x8 af[MR], bf[NR];
      #pragma unroll
      for (int m = 0; m < MR; ++m)
        af[m] = *reinterpret_cast<const bf16x8*>(&as[(rb + m*16 + lr) * 64 + kk + lk]);
      #pragma unroll
      for (int n = 0; n < NR; ++n)
        bf[n] = *reinterpret_cast<const bf16x8*>(&bs[(cb + n*16 + lr) * 64 + kk + lk]);
      #pragma unroll
      for (int m = 0; m < MR; ++m)
        #pragma unroll
        for (int n = 0; n < NR; ++n)
          acc[m][n] = MFMA(af[m], bf[n], acc[m][n], 0, 0, 0);
    }
  };

  stage(0, 0);
  __syncthreads();
  #pragma unroll
  for (int kt = 0; kt < 4; ++kt){
    if (kt < 3) stage((kt + 1) & 1, kt + 1);
    compute(kt & 1);
    if (kt < 3) __syncthreads();
  }

  if constexpr (LN){
    // TN == 256 == full row; n0 == 0. POST-LN: out = LN(acc+bias+res) bf16.
    #pragma unroll
    for (int m = 0; m < MR; ++m){
      #pragma unroll
      for (int j = 0; j < 4; ++j){
        const int lrow = rb + m*16 + rj + j;
        const int grow = m0 + lrow;
        float s = 0.f, q = 0.f;
        #pragma unroll
        for (int n = 0; n < NR; ++n){
          const int gcol = cb + n*16 + lr;
          float v = acc[m][n][j] + bias[gcol] + bf2f(res[(size_t)grow * 256 + gcol]);
          acc[m][n][j] = v;
          s += v; q += v * v;
        }
        #pragma unroll
        for (int o = 1; o < 16; o <<= 1){ s += __shfl_xor(s, o); q += __shfl_xor(q, o); }
        if (lr == 0){ redS[lrow*(WC+1) + wc] = s; redQ[lrow*(WC+1) + wc] = q; }
      }
    }
    __syncthreads();
    #pragma unroll
    for (int m = 0; m < MR; ++m){
      #pragma unroll
      for (int j = 0; j < 4; ++j){
        const int lrow = rb + m*16 + rj + j;
        const int grow = m0 + lrow;
        float s = 0.f, q = 0.f;
        #pragma unroll
        for (int c = 0; c < WC; ++c){ s += redS[lrow*(WC+1) + c]; q += redQ[lrow*(WC+1) + c]; }
        const float mean = s * (1.f/256.f);
        const float rstd = rsqrtf(q * (1.f/256.f) - mean*mean + 1e-5f);
        #pragma unroll
        for (int n = 0; n < NR; ++n){
          const int gcol = cb + n*16 + lr;
          ((u16*)outp)[(size_t)grow * 256 + gcol] =
              f2bf((acc[m][n][j] - mean) * rstd * lnw[gcol] + lnb[gcol]);
        }
      }
    }
  } else {
    #pragma unroll
    for (int m = 0; m < MR; ++m){
      #pragma unroll
      for (int n = 0; n < NR; ++n){
        const int gcol = n0 + cb + n*16 + lr;
        if (gcol < N){
          #pragma unroll
          for (int j = 0; j < 4; ++j){
            const int grow = m0 + rb + m*16 + rj + j;
            const size_t o = (size_t)grow * ldo + gcol;
            float v = acc[m][n][j];
            if (BIAS) v += bias[gcol];
            if (RES)  v += bf2f(res[o]);
            if (RELU) v = fmaxf(v, 0.f);
            if (F32OUT) ((float*)outp)[o] = v;
            else        ((u16*)outp)[o] = f2bf(v);
          }
        }
      }
    }
  }
}

// ---------------------------------------------------------------------------
// Attention v2: block per (b,h), 256 threads. K, V^T, Q staged in LDS from
// 64B-contiguous chunks (coalesced-ish); ALL fragments read from LDS.
// Causal-aware loop bounds skip fully-masked K tiles. Dynamic LDS 74.5 KB.
// QKV bf16 [NT][768] (Q 0..255, K 256..511, V 512..767; col=h*32+d).
// ---------------------------------------------------------------------------
__global__ __launch_bounds__(256) void attn2_k(
    const u16* __restrict__ QKV, u16* __restrict__ O)
{
  extern __shared__ char smem[];
  u16* Ks = (u16*)smem;            // [256][40]
  u16* Qs = Ks + 256 * 40;         // [64][40]
  u16* VT = Qs + 64 * 40;          // [32][264]
  u16* Ps = VT + 32 * 264;         // [64][264]

  const int bh = blockIdx.x, b = bh >> 3, h = bh & 7;
  const size_t rbase = (size_t)b * 256 * 768;
  const int qc = h * 32, kc = 256 + h * 32, vc = 512 + h * 32;
  const int t = threadIdx.x, l = t & 63, w = t >> 6;
  const int lr = l & 15, lk = (l >> 4) * 8, rj = (l >> 4) * 4;
  const int r4 = t >> 2, c8 = (t & 3) * 8;

  // stage K [256][40] and V^T [32][264]
  #pragma unroll
  for (int it = 0; it < 4; ++it){
    const int row = it * 64 + r4;
    *reinterpret_cast<uint4*>(Ks + row * 40 + c8) =
        *reinterpret_cast<const uint4*>(QKV + rbase + (size_t)row * 768 + kc + c8);
    union { uint4 q; u16 u[8]; } p;
    p.q = *reinterpret_cast<const uint4*>(QKV + rbase + (size_t)row * 768 + vc + c8);
    #pragma unroll
    for (int j2 = 0; j2 < 8; ++j2) VT[(c8 + j2) * 264 + row] = p.u[j2];
  }
  __syncthreads();

  bf16x8 kf[16];
  #pragma unroll
  for (int n = 0; n < 16; ++n)
    kf[n] = *reinterpret_cast<const bf16x8*>(Ks + (n*16 + lr) * 40 + lk);

  #pragma unroll 1
  for (int c = 0; c < 4; ++c){
    // stage Q chunk [64][40]
    *reinterpret_cast<uint4*>(Qs + r4 * 40 + c8) =
        *reinterpret_cast<const uint4*>(QKV + rbase + (size_t)(c*64 + r4) * 768 + qc + c8);
    __syncthreads();

    bf16x8 qa = *reinterpret_cast<const bf16x8*>(Qs + (w*16 + lr) * 40 + lk);
    const int nmax = 4 * (c + 1);
    f32x4 s[16];
    #pragma unroll
    for (int n = 0; n < 16; ++n){
      if (n < nmax){ f32x4 z = {}; s[n] = MFMA(qa, kf[n], z, 0, 0, 0); }
    }
    float inv[4];
    #pragma unroll
    for (int j = 0; j < 4; ++j){
      const int tq = c*64 + w*16 + rj + j;
      float m = -1e30f;
      #pragma unroll
      for (int n = 0; n < 16; ++n){
        if (n < nmax){
          float v = s[n][j] * 0.0625f;
          v = ((n*16 + lr) <= tq) ? v : -1e30f;
          s[n][j] = v;
          m = fmaxf(m, v);
        }
      }
      #pragma unroll
      for (int o = 1; o < 16; o <<= 1) m = fmaxf(m, __shfl_xor(m, o));
      float sum = 0.f;
      #pragma unroll
      for (int n = 0; n < 16; ++n){
        if (n < nmax){
          const float p = __expf(s[n][j] - m);
          sum += p;
          Ps[(w*16 + rj + j) * 264 + n*16 + lr] = f2bf(p);
        }
      }
      #pragma unroll
      for (int o = 1; o < 16; o <<= 1) sum += __shfl_xor(sum, o);
      inv[j] = 1.f / sum;
    }
    __syncthreads();

    f32x4 o0 = {}, o1 = {};
    #pragma unroll
    for (int k2 = 0; k2 < 8; ++k2){
      if (k2 < 2 * (c + 1)){
        bf16x8 pa  = *reinterpret_cast<const bf16x8*>(Ps + (w*16 + lr) * 264 + k2*32 + lk);
        bf16x8 vb0 = *reinterpret_cast<const bf16x8*>(VT + lr * 264 + k2*32 + lk);
        bf16x8 vb1 = *reinterpret_cast<const bf16x8*>(VT + (16 + lr) * 264 + k2*32 + lk);
        o0 = MFMA(pa, vb0, o0, 0, 0, 0);
        o1 = MFMA(pa, vb1, o1, 0, 0, 0);
      }
    }
    #pragma unroll
    for (int j = 0; j < 4; ++j){
      const int row = c*64 + w*16 + rj + j;
      u16* op = O + (size_t)(b*256 + row) * 256 + h*32;
      op[lr]      = f2bf(o0[j] * inv[j]);
      op[16 + lr] = f2bf(o1[j] * inv[j]);
    }
    __syncthreads();
  }
}

// ---------------------------------------------------------------------------
// Final LayerNorm, wave per row: bf16 -> bf16.
// ---------------------------------------------------------------------------
__global__ __launch_bounds__(256) void lnf_k(
    const u16* __restrict__ in, const float* __restrict__ w,
    const float* __restrict__ b, u16* __restrict__ out)
{
  const int wv = threadIdx.x >> 6, l = threadIdx.x & 63;
  const int r = blockIdx.x * 4 + wv;
  union { uint2 q; u16 u[4]; } iv;
  iv.q = *reinterpret_cast<const uint2*>(in + (size_t)r * 256 + l * 4);
  float v0 = bf2f(iv.u[0]), v1 = bf2f(iv.u[1]), v2 = bf2f(iv.u[2]), v3 = bf2f(iv.u[3]);
  float s = v0 + v1 + v2 + v3;
  float q = v0*v0 + v1*v1 + v2*v2 + v3*v3;
  #pragma unroll
  for (int o = 32; o; o >>= 1){ s += __shfl_xor(s, o); q += __shfl_xor(q, o); }
  const float mean = s * (1.f/256.f);
  const float rstd = rsqrtf(q * (1.f/256.f) - mean*mean + 1e-5f);
  float4 w4 = *reinterpret_cast<const float4*>(w + l * 4);
  float4 b4 = *reinterpret_cast<const float4*>(b + l * 4);
  union { u16 u[4]; uint2 q2; } p;
  p.u[0] = f2bf((v0 - mean) * rstd * w4.x + b4.x);
  p.u[1] = f2bf((v1 - mean) * rstd * w4.y + b4.y);
  p.u[2] = f2bf((v2 - mean) * rstd * w4.z + b4.z);
  p.u[3] = f2bf((v3 - mean) * rstd * w4.w + b4.w);
  *reinterpret_cast<uint2*>(out + (size_t)r * 256 + l * 4) = p.q2;
}

// ---------------------------------------------------------------------------
// NLL + loss
// ---------------------------------------------------------------------------
__global__ __launch_bounds__(256) void nll_k(
    const float* __restrict__ logits, const int* __restrict__ target,
    float* __restrict__ nll)
{
  const int w = threadIdx.x >> 6, l = threadIdx.x & 63;
  const int r = blockIdx.x * 4 + w;
  const float* row = logits + (size_t)r * 96;
  float v0 = row[l];
  float v1 = (l < 32) ? row[64 + l] : -1e30f;
  float m = fmaxf(v0, v1);
  #pragma unroll
  for (int o = 32; o; o >>= 1) m = fmaxf(m, __shfl_xor(m, o));
  float s = __expf(v0 - m) + ((l < 32) ? __expf(v1 - m) : 0.f);
  #pragma unroll
  for (int o = 32; o; o >>= 1) s += __shfl_xor(s, o);
  if (l == 0) nll[r] = logf(s) + m - row[target[r]];
}

__global__ __launch_bounds__(256) void loss_k(
    const float* __restrict__ nll, float* __restrict__ out)
{
  __shared__ float rs[4];
  float s = 0.f;
  for (int i = threadIdx.x; i < NT; i += 256) s += nll[i];
  #pragma unroll
  for (int o = 32; o; o >>= 1) s += __shfl_xor(s, o);
  if ((threadIdx.x & 63) == 0) rs[threadIdx.x >> 6] = s;
  __syncthreads();
  if (threadIdx.x == 0) out[0] = (rs[0] + rs[1] + rs[2] + rs[3]) * (1.f / 16384.f);
}

// ---------------------------------------------------------------------------
extern "C" void kernel_launch(void* const* d_in, const int* in_sizes, int n_in,
                              void* d_out, int out_size, void* d_ws, size_t ws_size,
                              hipStream_t stream)
{
  const int*   idx    = (const int*)  d_in[0];
  const int*   target = (const int*)  d_in[1];
  const float* tok    = (const float*)d_in[2];
  const float* pos    = (const float*)d_in[3];
  const float* bo     = (const float*)d_in[8];
  const float* b1     = (const float*)d_in[10];
  const float* b2     = (const float*)d_in[12];
  const float* ln1w   = (const float*)d_in[13];
  const float* ln1b   = (const float*)d_in[14];
  const float* ln2w   = (const float*)d_in[15];
  const float* ln2b   = (const float*)d_in[16];
  const float* lnfw   = (const float*)d_in[17];
  const float* lnfb   = (const float*)d_in[18];
  const float* blm    = (const float*)d_in[20];
  float* out = (float*)d_out;

  char* ws = (char*)d_ws;
  u16*   X   = (u16*)(ws);                 //  8 MiB bf16 residual
  u16*   QKV = (u16*)(ws + ( 8u << 20));   // 24 MiB bf16 [NT][768]
  u16*   O   = (u16*)(ws + (32u << 20));   //  8 MiB bf16 attn out
  u16*   hB  = (u16*)(ws + (40u << 20));   //  8 MiB bf16 MLP hidden
  u16*   Xf  = (u16*)(ws + (48u << 20));   //  8 MiB bf16 final-LN out
  u16*   WT  = (u16*)(ws + (56u << 20));   // ~4.63 MiB bf16 weights
  float* nl  = (float*)(ws + (62u << 20)); // 64 KiB

  // dynamic LDS sizes: 2*(TM+TN)*64*2 + 2*TM*(WC+1)*4
  const size_t SM_QKV = (size_t)2*(128+128)*64*2 + 2*128*5*4;   // 70656
  const size_t SM_LN  = (size_t)2*(64+256)*64*2 + 2*64*9*4;     // 86528
  const size_t SM_W1  = (size_t)2*(64+128)*64*2 + 2*64*5*4;     // 51712
  const size_t SM_AT  = (size_t)(256*40 + 64*40 + 32*264 + 64*264) * 2; // 76288

  wconv_k<<<dim3(4, 4, 37), 256, 0, stream>>>(
      (const float*)d_in[4], (const float*)d_in[5], (const float*)d_in[6],
      (const float*)d_in[7], (const float*)d_in[9], (const float*)d_in[11],
      (const float*)d_in[19], WT);
  embed_k<<<NT / 4, 256, 0, stream>>>(idx, tok, pos, X);

  for (int l = 0; l < LAYERS; ++l){
    const u16* wqkv = WT + (size_t)l * 196608;
    const u16* wo   = WT + 1179648 + (size_t)(0*6 + l) * 65536;
    const u16* w1   = WT + 1179648 + (size_t)(1*6 + l) * 65536;
    const u16* w2   = WT + 1179648 + (size_t)(2*6 + l) * 65536;

    gemm3_k<128,128,512,2,4, false,false,false,false,false>
        <<<dim3(128, 6), 512, SM_QKV, stream>>>(
        X, wqkv, nullptr, nullptr, QKV, nullptr, nullptr, 768, 768);
    attn2_k<<<512, 256, SM_AT, stream>>>(QKV, O);
    gemm3_k<64,256,1024,2,8, true,false,true,true,false>
        <<<dim3(256, 1), 1024, SM_LN, stream>>>(
        O, wo, bo + l*256, X, X, ln1w + l*256, ln1b + l*256, 256, 256);
    gemm3_k<64,128,512,2,4, true,true,false,false,false>
        <<<dim3(256, 2), 512, SM_W1, stream>>>(
        X, w1, b1 + l*256, nullptr, hB, nullptr, nullptr, 256, 256);
    gemm3_k<64,256,1024,2,8, true,false,true,true,false>
        <<<dim3(256, 1), 1024, SM_LN, stream>>>(
        hB, w2, b2 + l*256, X, X, ln2w + l*256, ln2b + l*256, 256, 256);
  }

  lnf_k<<<NT / 4, 256, 0, stream>>>(X, lnfw, lnfb, Xf);
  gemm3_k<64,128,512,2,4, true,false,false,false,true>
      <<<dim3(256, 1), 512, SM_W1, stream>>>(
      Xf, WT + 2359296, blm, nullptr, out, nullptr, nullptr, 96, 96);
  nll_k<<<NT / 4, 256, 0, stream>>>(out, target, nl);
  loss_k<<<1, 256, 0, stream>>>(nl, out + (size_t)NT * 96);
}

// Round 10
// 584.382 us; speedup vs baseline: 1.8376x; 1.0617x over previous
//
#include <hip/hip_runtime.h>

typedef unsigned short u16;

#define NT   16384
#define LAYERS 6

using bf16x8 = __attribute__((ext_vector_type(8))) __bf16;
using f32x4  = __attribute__((ext_vector_type(4))) float;

#define MFMA __builtin_amdgcn_mfma_f32_16x16x32_bf16

__device__ __forceinline__ u16 f2bf(float x){
  unsigned u = __float_as_uint(x);
  u += 0x7fffu + ((u >> 16) & 1u);
  return (u16)(u >> 16);
}
__device__ __forceinline__ float bf2f(u16 u){
  return __uint_as_float(((unsigned)u) << 16);
}

__device__ __forceinline__ void gll16(const u16* g, u16* l){
  __builtin_amdgcn_global_load_lds(
      (const __attribute__((address_space(1))) unsigned int*)g,
      (__attribute__((address_space(3))) unsigned int*)l, 16, 0, 0);
}

// ---------------------------------------------------------------------------
// Weight transpose+convert: fp32 [K=256][N] -> bf16 [Npad][256] (row n = W[:,n])
// ---------------------------------------------------------------------------
__global__ __launch_bounds__(256) void wconv_k(
    const float* __restrict__ Wq, const float* __restrict__ Wk,
    const float* __restrict__ Wv, const float* __restrict__ Wo,
    const float* __restrict__ W1, const float* __restrict__ W2,
    const float* __restrict__ Wlm, u16* __restrict__ WT)
{
  __shared__ float tile[64][65];
  const int z = blockIdx.z;
  const float* src; u16* dst; int N = 256, Npad = 256;
  if (z < 18){
    const int l = z / 3, which = z % 3;
    const float* a[3] = {Wq, Wk, Wv};
    src = a[which] + (size_t)l * 65536;
    dst = WT + (size_t)l * 196608 + (size_t)which * 65536;
  } else if (z < 36){
    const int i = z - 18, j = i / 6, l = i % 6;
    const float* a[3] = {Wo, W1, W2};
    src = a[j] + (size_t)l * 65536;
    dst = WT + 1179648 + (size_t)(j * 6 + l) * 65536;
  } else {
    src = Wlm; dst = WT + 2359296; N = 96; Npad = 128;
  }
  const int n0 = blockIdx.y * 64, k0 = blockIdx.x * 64;
  if (n0 >= Npad) return;
  const int c = threadIdx.x & 63, r0 = threadIdx.x >> 6;
  #pragma unroll
  for (int i = 0; i < 16; ++i){
    const int r = r0 + i * 4;
    tile[r][c] = (n0 + c < N) ? src[(size_t)(k0 + r) * N + n0 + c] : 0.f;
  }
  __syncthreads();
  #pragma unroll
  for (int i = 0; i < 16; ++i){
    const int cp = r0 + i * 4;
    dst[(size_t)(n0 + cp) * 256 + k0 + c] = f2bf(tile[c][cp]);
  }
}

// ---------------------------------------------------------------------------
// Embedding: wave per row -> X bf16.
// ---------------------------------------------------------------------------
__global__ __launch_bounds__(256) void embed_k(
    const int* __restrict__ idx, const float* __restrict__ tok,
    const float* __restrict__ pos, u16* __restrict__ X)
{
  const int w = threadIdx.x >> 6, l = threadIdx.x & 63;
  const int r = blockIdx.x * 4 + w;
  const int id = idx[r];
  float4 tv = *reinterpret_cast<const float4*>(tok + (size_t)id * 256 + l * 4);
  float4 pv = *reinterpret_cast<const float4*>(pos + (size_t)(r & 255) * 256 + l * 4);
  union { u16 u[4]; uint2 q; } p;
  p.u[0] = f2bf(tv.x + pv.x); p.u[1] = f2bf(tv.y + pv.y);
  p.u[2] = f2bf(tv.z + pv.z); p.u[3] = f2bf(tv.w + pv.w);
  *reinterpret_cast<uint2*>(X + (size_t)r * 256 + l * 4) = p.q;
}

// ---------------------------------------------------------------------------
// GEMM v3 (layer-0 QKV only): both operands LDS-staged, double-buffered.
// ---------------------------------------------------------------------------
template<int TM, int TN, int THREADS, int WR, int WC>
__global__ __launch_bounds__(THREADS) void gemm3_k(
    const u16* __restrict__ A, const u16* __restrict__ WT,
    u16* __restrict__ outp, int ldo)
{
  constexpr int MR = TM / (WR * 16), NR = TN / (WC * 16);
  extern __shared__ char smem[];
  u16* As = (u16*)smem;
  u16* Bs = As + 2 * TM * 64;

  const int t = threadIdx.x, l = t & 63, w = t >> 6;
  const int wr = w / WC, wc = w % WC;
  const int m0 = blockIdx.x * TM, n0 = blockIdx.y * TN;
  const int lr = l & 15, lk = (l >> 4) * 8, rj = (l >> 4) * 4;
  const int rb = wr * (TM / WR), cb = wc * (TN / WC);
  f32x4 acc[MR][NR] = {};

  auto stage = [&](int buf, int kt){
    const int k0 = kt * 64;
    u16* as = As + buf * (TM * 64);
    u16* bs = Bs + buf * (TN * 64);
    #pragma unroll
    for (int ci = t; ci < TM * 8; ci += THREADS){
      const int eo = ci * 8;
      gll16(A + (size_t)(m0 + (eo >> 6)) * 256 + k0 + (eo & 63), as + eo);
    }
    #pragma unroll
    for (int ci = t; ci < TN * 8; ci += THREADS){
      const int eo = ci * 8;
      gll16(WT + (size_t)(n0 + (eo >> 6)) * 256 + k0 + (eo & 63), bs + eo);
    }
  };
  auto compute = [&](int buf){
    const u16* as = As + buf * (TM * 64);
    const u16* bs = Bs + buf * (TN * 64);
    #pragma unroll
    for (int kk = 0; kk < 64; kk += 32){
      bf16x8 af[MR], bfv[NR];
      #pragma unroll
      for (int m = 0; m < MR; ++m)
        af[m] = *reinterpret_cast<const bf16x8*>(&as[(rb + m*16 + lr) * 64 + kk + lk]);
      #pragma unroll
      for (int n = 0; n < NR; ++n)
        bfv[n] = *reinterpret_cast<const bf16x8*>(&bs[(cb + n*16 + lr) * 64 + kk + lk]);
      #pragma unroll
      for (int m = 0; m < MR; ++m)
        #pragma unroll
        for (int n = 0; n < NR; ++n)
          acc[m][n] = MFMA(af[m], bfv[n], acc[m][n], 0, 0, 0);
    }
  };

  stage(0, 0);
  __syncthreads();
  #pragma unroll
  for (int kt = 0; kt < 4; ++kt){
    if (kt < 3) stage((kt + 1) & 1, kt + 1);
    compute(kt & 1);
    if (kt < 3) __syncthreads();
  }
  #pragma unroll
  for (int m = 0; m < MR; ++m)
    #pragma unroll
    for (int n = 0; n < NR; ++n){
      const int gcol = n0 + cb + n*16 + lr;
      #pragma unroll
      for (int j = 0; j < 4; ++j){
        const int grow = m0 + rb + m*16 + rj + j;
        outp[(size_t)grow * ldo + gcol] = f2bf(acc[m][n][j]);
      }
    }
}

// ---------------------------------------------------------------------------
// Fused layer-tail kernel: 256 blocks x 1024 thr (16 waves, 2x8), block owns
// 64 rows.
// Phase 1: acc = A[64][256] @ Bw1 (+bias1, +res X) -> post-LN -> X (global) and
//          Xn (LDS, stride 264 => 2-way bank aliasing only).
// [LNF]:   in-place final LN on Xn.
// Phase 2: out2 = Xn @ Bw2 (+bias2, relu / f32-out); A-frags straight from LDS;
//          B chunks (TN2 cols) double-buffered; first stage pre-issued during
//          phase-1 epilogue.
// ---------------------------------------------------------------------------
template<int TN2, int NCH, bool RELU2, bool BIAS2, bool LNF, bool F32O2>
__global__ __launch_bounds__(1024) void gemmF_k(
    const u16* __restrict__ A, const u16* __restrict__ Bw1,
    const float* __restrict__ bias1, u16* __restrict__ X,
    const float* __restrict__ lnw, const float* __restrict__ lnb,
    const u16* __restrict__ Bw2, const float* __restrict__ bias2,
    void* __restrict__ out2, int ldo2,
    const float* __restrict__ lnfw, const float* __restrict__ lnfb)
{
  constexpr int NR2 = TN2 / 128;
  extern __shared__ char smem[];
  u16* As = (u16*)smem;          // [2][64*64]
  u16* Bs = As + 8192;           // [2][256*64]
  u16* Xn = Bs + 32768;          // [64][264]
  float* redS = (float*)(Xn + 16896);
  float* redQ = redS + 64 * 9;

  const int t = threadIdx.x, l = t & 63, w = t >> 6;
  const int wr = w >> 3, wc = w & 7;
  const int m0 = blockIdx.x * 64;
  const int lr = l & 15, lk = (l >> 4) * 8, rj = (l >> 4) * 4;
  const int rb = wr * 32, cb = wc * 32;
  const int cb2 = wc * (TN2 / 8);

  auto stage1 = [&](int buf, int kt){
    const int k0 = kt * 64;
    u16* as = As + buf * 4096;
    u16* bs = Bs + buf * 16384;
    if (t < 512){
      const int eo = t * 8;
      gll16(A + (size_t)(m0 + (eo >> 6)) * 256 + k0 + (eo & 63), as + eo);
    }
    #pragma unroll
    for (int i = 0; i < 2; ++i){
      const int eo = (i * 1024 + t) * 8;
      gll16(Bw1 + (size_t)(eo >> 6) * 256 + k0 + (eo & 63), bs + eo);
    }
  };
  auto stage2 = [&](int buf, int nc, int kt){
    const int k0 = kt * 64;
    u16* bs = Bs + buf * 16384;
    #pragma unroll
    for (int i = 0; i < TN2 / 128; ++i){
      const int eo = (i * 1024 + t) * 8;
      gll16(Bw2 + (size_t)(nc * TN2 + (eo >> 6)) * 256 + k0 + (eo & 63), bs + eo);
    }
  };

  // ---- phase 1 ----
  f32x4 acc[2][2] = {};
  stage1(0, 0);
  __syncthreads();
  #pragma unroll
  for (int kt = 0; kt < 4; ++kt){
    if (kt < 3) stage1((kt + 1) & 1, kt + 1);
    const u16* as = As + (kt & 1) * 4096;
    const u16* bs = Bs + (kt & 1) * 16384;
    #pragma unroll
    for (int kk = 0; kk < 64; kk += 32){
      bf16x8 af[2], bfv[2];
      #pragma unroll
      for (int m = 0; m < 2; ++m)
        af[m] = *reinterpret_cast<const bf16x8*>(&as[(rb + m*16 + lr) * 64 + kk + lk]);
      #pragma unroll
      for (int n = 0; n < 2; ++n)
        bfv[n] = *reinterpret_cast<const bf16x8*>(&bs[(cb + n*16 + lr) * 64 + kk + lk]);
      #pragma unroll
      for (int m = 0; m < 2; ++m)
        #pragma unroll
        for (int n = 0; n < 2; ++n)
          acc[m][n] = MFMA(af[m], bfv[n], acc[m][n], 0, 0, 0);
    }
    if (kt < 3) __syncthreads();
  }

  // pre-issue phase-2 chunk 0 into buf 0 (buf0 idle since kt=2 barrier)
  stage2(0, 0, 0);

  // ---- LN epilogue: v = acc + bias1 + X; X = Xn = LN(v) ----
  #pragma unroll
  for (int m = 0; m < 2; ++m){
    #pragma unroll
    for (int j = 0; j < 4; ++j){
      const int lrow = rb + m*16 + rj + j;
      float s = 0.f, q = 0.f;
      #pragma unroll
      for (int n = 0; n < 2; ++n){
        const int col = cb + n*16 + lr;
        float v = acc[m][n][j] + bias1[col] + bf2f(X[(size_t)(m0 + lrow) * 256 + col]);
        acc[m][n][j] = v;
        s += v; q += v * v;
      }
      #pragma unroll
      for (int o = 1; o < 16; o <<= 1){ s += __shfl_xor(s, o); q += __shfl_xor(q, o); }
      if (lr == 0){ redS[lrow*9 + wc] = s; redQ[lrow*9 + wc] = q; }
    }
  }
  __syncthreads();
  #pragma unroll
  for (int m = 0; m < 2; ++m){
    #pragma unroll
    for (int j = 0; j < 4; ++j){
      const int lrow = rb + m*16 + rj + j;
      float s = 0.f, q = 0.f;
      #pragma unroll
      for (int c = 0; c < 8; ++c){ s += redS[lrow*9 + c]; q += redQ[lrow*9 + c]; }
      const float mean = s * (1.f/256.f);
      const float rstd = rsqrtf(q * (1.f/256.f) - mean*mean + 1e-5f);
      #pragma unroll
      for (int n = 0; n < 2; ++n){
        const int col = cb + n*16 + lr;
        const u16 y = f2bf((acc[m][n][j] - mean) * rstd * lnw[col] + lnb[col]);
        Xn[lrow*264 + col] = y;
        X[(size_t)(m0 + lrow) * 256 + col] = y;
      }
    }
  }

  if constexpr (LNF){
    __syncthreads();
    // in-place final LN on Xn: 16 waves x 4 rows
    #pragma unroll
    for (int rr = 0; rr < 4; ++rr){
      const int row = w * 4 + rr;
      union { uint2 q2; u16 u[4]; } iv;
      iv.q2 = *reinterpret_cast<const uint2*>(Xn + row*264 + l*4);
      float v0 = bf2f(iv.u[0]), v1 = bf2f(iv.u[1]), v2 = bf2f(iv.u[2]), v3 = bf2f(iv.u[3]);
      float s = v0 + v1 + v2 + v3;
      float q = v0*v0 + v1*v1 + v2*v2 + v3*v3;
      #pragma unroll
      for (int o = 1; o < 64; o <<= 1){ s += __shfl_xor(s, o); q += __shfl_xor(q, o); }
      const float mean = s * (1.f/256.f);
      const float rstd = rsqrtf(q * (1.f/256.f) - mean*mean + 1e-5f);
      union { u16 u[4]; uint2 q2; } p;
      p.u[0] = f2bf((v0 - mean) * rstd * lnfw[l*4+0] + lnfb[l*4+0]);
      p.u[1] = f2bf((v1 - mean) * rstd * lnfw[l*4+1] + lnfb[l*4+1]);
      p.u[2] = f2bf((v2 - mean) * rstd * lnfw[l*4+2] + lnfb[l*4+2]);
      p.u[3] = f2bf((v3 - mean) * rstd * lnfw[l*4+3] + lnfb[l*4+3]);
      *reinterpret_cast<uint2*>(Xn + row*264 + l*4) = p.q2;
    }
  }
  __syncthreads();   // Xn ready for all waves; stage2(0,0,0) drained

  // ---- phase 2: out2 = Xn @ Bw2 ----
  #pragma unroll 1
  for (int nc = 0; nc < NCH; ++nc){
    f32x4 a2[2][NR2] = {};
    #pragma unroll
    for (int kt = 0; kt < 4; ++kt){
      const int s = nc*4 + kt, nx = s + 1;
      if (nx < NCH*4) stage2(nx & 1, nx >> 2, nx & 3);
      const u16* bs = Bs + (s & 1) * 16384;
      #pragma unroll
      for (int kk2 = 0; kk2 < 64; kk2 += 32){
        const int kk = kt*64 + kk2;
        bf16x8 af[2], bfv[NR2];
        #pragma unroll
        for (int m = 0; m < 2; ++m)
          af[m] = *reinterpret_cast<const bf16x8*>(Xn + (rb + m*16 + lr)*264 + kk + lk);
        #pragma unroll
        for (int n = 0; n < NR2; ++n)
          bfv[n] = *reinterpret_cast<const bf16x8*>(&bs[(cb2 + n*16 + lr)*64 + kk2 + lk]);
        #pragma unroll
        for (int m = 0; m < 2; ++m)
          #pragma unroll
          for (int n = 0; n < NR2; ++n)
            a2[m][n] = MFMA(af[m], bfv[n], a2[m][n], 0, 0, 0);
      }
      if (nx < NCH*4) __syncthreads();
    }
    #pragma unroll
    for (int m = 0; m < 2; ++m){
      #pragma unroll
      for (int n = 0; n < NR2; ++n){
        const int col = nc*TN2 + cb2 + n*16 + lr;
        #pragma unroll
        for (int j = 0; j < 4; ++j){
          const int grow = m0 + rb + m*16 + rj + j;
          float v = a2[m][n][j];
          if (BIAS2) v += bias2[col];
          if (RELU2) v = fmaxf(v, 0.f);
          if (F32O2){
            if (col < 96) ((float*)out2)[(size_t)grow * ldo2 + col] = v;
          } else {
            ((u16*)out2)[(size_t)grow * ldo2 + col] = f2bf(v);
          }
        }
      }
    }
  }
}

// ---------------------------------------------------------------------------
// Attention: block per (b,h); K/V^T/Q LDS-staged; causal skip.
// ---------------------------------------------------------------------------
__global__ __launch_bounds__(256) void attn2_k(
    const u16* __restrict__ QKV, u16* __restrict__ O)
{
  extern __shared__ char smem[];
  u16* Ks = (u16*)smem;            // [256][40]
  u16* Qs = Ks + 256 * 40;         // [64][40]
  u16* VT = Qs + 64 * 40;          // [32][264]
  u16* Ps = VT + 32 * 264;         // [64][264]

  const int bh = blockIdx.x, b = bh >> 3, h = bh & 7;
  const size_t rbase = (size_t)b * 256 * 768;
  const int qc = h * 32, kc = 256 + h * 32, vc = 512 + h * 32;
  const int t = threadIdx.x, l = t & 63, w = t >> 6;
  const int lr = l & 15, lk = (l >> 4) * 8, rj = (l >> 4) * 4;
  const int r4 = t >> 2, c8 = (t & 3) * 8;

  #pragma unroll
  for (int it = 0; it < 4; ++it){
    const int row = it * 64 + r4;
    *reinterpret_cast<uint4*>(Ks + row * 40 + c8) =
        *reinterpret_cast<const uint4*>(QKV + rbase + (size_t)row * 768 + kc + c8);
    union { uint4 q; u16 u[8]; } p;
    p.q = *reinterpret_cast<const uint4*>(QKV + rbase + (size_t)row * 768 + vc + c8);
    #pragma unroll
    for (int j2 = 0; j2 < 8; ++j2) VT[(c8 + j2) * 264 + row] = p.u[j2];
  }
  __syncthreads();

  bf16x8 kf[16];
  #pragma unroll
  for (int n = 0; n < 16; ++n)
    kf[n] = *reinterpret_cast<const bf16x8*>(Ks + (n*16 + lr) * 40 + lk);

  #pragma unroll 1
  for (int c = 0; c < 4; ++c){
    *reinterpret_cast<uint4*>(Qs + r4 * 40 + c8) =
        *reinterpret_cast<const uint4*>(QKV + rbase + (size_t)(c*64 + r4) * 768 + qc + c8);
    __syncthreads();

    bf16x8 qa = *reinterpret_cast<const bf16x8*>(Qs + (w*16 + lr) * 40 + lk);
    const int nmax = 4 * (c + 1);
    f32x4 s[16];
    #pragma unroll
    for (int n = 0; n < 16; ++n){
      if (n < nmax){ f32x4 z = {}; s[n] = MFMA(qa, kf[n], z, 0, 0, 0); }
    }
    float inv[4];
    #pragma unroll
    for (int j = 0; j < 4; ++j){
      const int tq = c*64 + w*16 + rj + j;
      float m = -1e30f;
      #pragma unroll
      for (int n = 0; n < 16; ++n){
        if (n < nmax){
          float v = s[n][j] * 0.0625f;
          v = ((n*16 + lr) <= tq) ? v : -1e30f;
          s[n][j] = v;
          m = fmaxf(m, v);
        }
      }
      #pragma unroll
      for (int o = 1; o < 16; o <<= 1) m = fmaxf(m, __shfl_xor(m, o));
      float sum = 0.f;
      #pragma unroll
      for (int n = 0; n < 16; ++n){
        if (n < nmax){
          const float p = __expf(s[n][j] - m);
          sum += p;
          Ps[(w*16 + rj + j) * 264 + n*16 + lr] = f2bf(p);
        }
      }
      #pragma unroll
      for (int o = 1; o < 16; o <<= 1) sum += __shfl_xor(sum, o);
      inv[j] = 1.f / sum;
    }
    __syncthreads();

    f32x4 o0 = {}, o1 = {};
    #pragma unroll
    for (int k2 = 0; k2 < 8; ++k2){
      if (k2 < 2 * (c + 1)){
        bf16x8 pa  = *reinterpret_cast<const bf16x8*>(Ps + (w*16 + lr) * 264 + k2*32 + lk);
        bf16x8 vb0 = *reinterpret_cast<const bf16x8*>(VT + lr * 264 + k2*32 + lk);
        bf16x8 vb1 = *reinterpret_cast<const bf16x8*>(VT + (16 + lr) * 264 + k2*32 + lk);
        o0 = MFMA(pa, vb0, o0, 0, 0, 0);
        o1 = MFMA(pa, vb1, o1, 0, 0, 0);
      }
    }
    #pragma unroll
    for (int j = 0; j < 4; ++j){
      const int row = c*64 + w*16 + rj + j;
      u16* op = O + (size_t)(b*256 + row) * 256 + h*32;
      op[lr]      = f2bf(o0[j] * inv[j]);
      op[16 + lr] = f2bf(o1[j] * inv[j]);
    }
    __syncthreads();
  }
}

// ---------------------------------------------------------------------------
// NLL + loss
// ---------------------------------------------------------------------------
__global__ __launch_bounds__(256) void nll_k(
    const float* __restrict__ logits, const int* __restrict__ target,
    float* __restrict__ nll)
{
  const int w = threadIdx.x >> 6, l = threadIdx.x & 63;
  const int r = blockIdx.x * 4 + w;
  const float* row = logits + (size_t)r * 96;
  float v0 = row[l];
  float v1 = (l < 32) ? row[64 + l] : -1e30f;
  float m = fmaxf(v0, v1);
  #pragma unroll
  for (int o = 32; o; o >>= 1) m = fmaxf(m, __shfl_xor(m, o));
  float s = __expf(v0 - m) + ((l < 32) ? __expf(v1 - m) : 0.f);
  #pragma unroll
  for (int o = 32; o; o >>= 1) s += __shfl_xor(s, o);
  if (l == 0) nll[r] = logf(s) + m - row[target[r]];
}

__global__ __launch_bounds__(256) void loss_k(
    const float* __restrict__ nll, float* __restrict__ out)
{
  __shared__ float rs[4];
  float s = 0.f;
  for (int i = threadIdx.x; i < NT; i += 256) s += nll[i];
  #pragma unroll
  for (int o = 32; o; o >>= 1) s += __shfl_xor(s, o);
  if ((threadIdx.x & 63) == 0) rs[threadIdx.x >> 6] = s;
  __syncthreads();
  if (threadIdx.x == 0) out[0] = (rs[0] + rs[1] + rs[2] + rs[3]) * (1.f / 16384.f);
}

// ---------------------------------------------------------------------------
extern "C" void kernel_launch(void* const* d_in, const int* in_sizes, int n_in,
                              void* d_out, int out_size, void* d_ws, size_t ws_size,
                              hipStream_t stream)
{
  const int*   idx    = (const int*)  d_in[0];
  const int*   target = (const int*)  d_in[1];
  const float* tok    = (const float*)d_in[2];
  const float* pos    = (const float*)d_in[3];
  const float* bo     = (const float*)d_in[8];
  const float* b1     = (const float*)d_in[10];
  const float* b2     = (const float*)d_in[12];
  const float* ln1w   = (const float*)d_in[13];
  const float* ln1b   = (const float*)d_in[14];
  const float* ln2w   = (const float*)d_in[15];
  const float* ln2b   = (const float*)d_in[16];
  const float* lnfw   = (const float*)d_in[17];
  const float* lnfb   = (const float*)d_in[18];
  const float* blm    = (const float*)d_in[20];
  float* out = (float*)d_out;

  char* ws = (char*)d_ws;
  u16*   X   = (u16*)(ws);                 //  8 MiB bf16 residual
  u16*   QKV = (u16*)(ws + ( 8u << 20));   // 24 MiB bf16 [NT][768]
  u16*   O   = (u16*)(ws + (32u << 20));   //  8 MiB bf16 attn out
  u16*   hB  = (u16*)(ws + (40u << 20));   //  8 MiB bf16 MLP hidden
  u16*   WT  = (u16*)(ws + (48u << 20));   // ~4.63 MiB bf16 weights
  float* nl  = (float*)(ws + (56u << 20)); // 64 KiB

  const size_t SM_QKV = (size_t)2*(128+128)*64*2;                       // 65536
  const size_t SM_AT  = (size_t)(256*40 + 64*40 + 32*264 + 64*264) * 2; // 76288
  const size_t SM_F   = (size_t)(8192 + 32768 + 16896)*2 + 64*9*4*2;    // 120320

  wconv_k<<<dim3(4, 4, 37), 256, 0, stream>>>(
      (const float*)d_in[4], (const float*)d_in[5], (const float*)d_in[6],
      (const float*)d_in[7], (const float*)d_in[9], (const float*)d_in[11],
      (const float*)d_in[19], WT);
  embed_k<<<NT / 4, 256, 0, stream>>>(idx, tok, pos, X);

  // layer-0 QKV
  gemm3_k<128,128,512,2,4><<<dim3(128, 6), 512, SM_QKV, stream>>>(
      X, WT, QKV, 768);

  for (int l = 0; l < LAYERS; ++l){
    const u16* wo = WT + 1179648 + (size_t)(0*6 + l) * 65536;
    const u16* w1 = WT + 1179648 + (size_t)(1*6 + l) * 65536;
    const u16* w2 = WT + 1179648 + (size_t)(2*6 + l) * 65536;

    attn2_k<<<512, 256, SM_AT, stream>>>(QKV, O);

    // V1: X = LN1(X + O@wo + bo); hB = relu(X@w1 + b1)
    gemmF_k<256,1,true,true,false,false><<<256, 1024, SM_F, stream>>>(
        O, wo, bo + l*256, X, ln1w + l*256, ln1b + l*256,
        w1, b1 + l*256, hB, 256, nullptr, nullptr);

    if (l < LAYERS - 1){
      // V2: X = LN2(X + hB@w2 + b2); QKV = X @ wqkv[l+1]
      gemmF_k<256,3,false,false,false,false><<<256, 1024, SM_F, stream>>>(
          hB, w2, b2 + l*256, X, ln2w + l*256, ln2b + l*256,
          WT + (size_t)(l+1) * 196608, nullptr, QKV, 768, nullptr, nullptr);
    } else {
      // V3: X = LN2(...); Xf = LNf(X); logits = Xf @ Wlm + blm
      gemmF_k<128,1,false,true,true,true><<<256, 1024, SM_F, stream>>>(
          hB, w2, b2 + l*256, X, ln2w + l*256, ln2b + l*256,
          WT + 2359296, blm, out, 96, lnfw, lnfb);
    }
  }

  nll_k<<<NT / 4, 256, 0, stream>>>(out, target, nl);
  loss_k<<<1, 256, 0, stream>>>(nl, out + (size_t)NT * 96);
}